// Round 4
// baseline (216.649 us; speedup 1.0000x reference)
//
#include <hip/hip_runtime.h>
#include <cstdint>
#include <cstddef>

#define SL 4096
#define DM 768

typedef short s16x8 __attribute__((ext_vector_type(8)));
typedef unsigned short u16x8 __attribute__((ext_vector_type(8)));
typedef unsigned short u16x4 __attribute__((ext_vector_type(4)));
typedef float f32x4 __attribute__((ext_vector_type(4)));
typedef float f32x16 __attribute__((ext_vector_type(16)));
typedef unsigned int u32x4 __attribute__((ext_vector_type(4)));

__device__ __forceinline__ unsigned short f2bf(float f) {
  unsigned u = __float_as_uint(f);
  u = u + 0x7fffu + ((u >> 16) & 1u);   // round-to-nearest-even
  return (unsigned short)(u >> 16);
}

// 16B-block XOR swizzle within a 64-short (128B) row (guide G4/T2) — GEMM kernels.
__device__ __forceinline__ int swz(int row, int col) {
  return (row << 6) + ((((col >> 3) ^ row) & 7) << 3) + (col & 7);
}

// attention swizzle: also folds row>>3 so rows ≡ (mod 8) land in distinct 16B slots
// (32-row A-frag reads of the 32x32 MFMA would otherwise 4-way conflict)
__device__ __forceinline__ int aswz(int row, int col) {
  return (row << 6) + ((((col >> 3) ^ row ^ (row >> 3)) & 7) << 3) + (col & 7);
}

// async global->LDS, 16B per lane; dest = wave-uniform base + lane*16 (linear),
// source per-lane address carries the swizzle (m173 pattern).
#define ASYNC16(G, L)                                                        \
  __builtin_amdgcn_global_load_lds(                                          \
      (const __attribute__((address_space(1))) void*)(G),                    \
      (__attribute__((address_space(3))) void*)(L), 16, 0, 0)

#define WAITB()                                   \
  do {                                            \
    asm volatile("s_waitcnt vmcnt(0)" ::: "memory"); \
    __builtin_amdgcn_s_barrier();                 \
  } while (0)

extern "C" __global__ __launch_bounds__(256) void k_cvt(
    const float* __restrict__ in, unsigned short* __restrict__ out, int n) {
  int i = (blockIdx.x * 256 + threadIdx.x) * 4;
  if (i >= n) return;
  f32x4 v = *reinterpret_cast<const f32x4*>(in + i);
  u16x4 o;
  o[0] = f2bf(v[0]); o[1] = f2bf(v[1]); o[2] = f2bf(v[2]); o[3] = f2bf(v[3]);
  *reinterpret_cast<u16x4*>(out + i) = o;
}

// fp32 [R][C] -> bf16 [C][R], 64x64 tiles
extern "C" __global__ __launch_bounds__(256) void k_tr(
    const float* __restrict__ in, unsigned short* __restrict__ out, int R, int C) {
  __shared__ float tile[64][65];
  const int t = threadIdx.x;
  const int r0 = blockIdx.y * 64, c0 = blockIdx.x * 64;
  const int lr = t >> 2, lcb = (t & 3) * 16;
  #pragma unroll
  for (int j = 0; j < 16; j += 4) {
    f32x4 v = *reinterpret_cast<const f32x4*>(in + (size_t)(r0 + lr) * C + c0 + lcb + j);
    tile[lr][lcb + j + 0] = v[0];
    tile[lr][lcb + j + 1] = v[1];
    tile[lr][lcb + j + 2] = v[2];
    tile[lr][lcb + j + 3] = v[3];
  }
  __syncthreads();
  #pragma unroll
  for (int j = 0; j < 16; j += 4) {
    u16x4 o;
    o[0] = f2bf(tile[lcb + j + 0][lr]);
    o[1] = f2bf(tile[lcb + j + 1][lr]);
    o[2] = f2bf(tile[lcb + j + 2][lr]);
    o[3] = f2bf(tile[lcb + j + 3][lr]);
    *reinterpret_cast<u16x4*>(out + (size_t)(c0 + lr) * R + r0 + lcb + j) = o;
  }
}

__device__ __forceinline__ void gemm_body(
    const unsigned short* al, const unsigned short* bl, f32x4* acc,
    int wv, int l15, int lg) {
  #pragma unroll
  for (int kc = 0; kc < 2; kc++) {
    s16x8 af = *reinterpret_cast<const s16x8*>(&al[swz(wv * 16 + l15, kc * 32 + lg * 8)]);
    #pragma unroll
    for (int nt = 0; nt < 4; nt++) {
      s16x8 bfr = *reinterpret_cast<const s16x8*>(&bl[swz(nt * 16 + l15, kc * 32 + lg * 8)]);
      acc[nt] = __builtin_amdgcn_mfma_f32_16x16x32_bf16(af, bfr, acc[nt], 0, 0, 0);
    }
  }
}

// QKV GEMM (async dbuf): q pre-scaled by 0.125*log2(e), k row-major, v transposed
extern "C" __global__ __launch_bounds__(256) void k_qkv(
    const unsigned short* __restrict__ xbf, const unsigned short* __restrict__ wt,
    const float* __restrict__ bias, unsigned short* __restrict__ qb,
    unsigned short* __restrict__ kbo, unsigned short* __restrict__ vt) {
  __shared__ alignas(16) unsigned short a_lds[2][4096];
  __shared__ alignas(16) unsigned short b_lds[2][4096];
  const int t = threadIdx.x, wv = t >> 6, l = t & 63;
  const int l15 = l & 15, lg = l >> 4;
  const int m0 = blockIdx.y * 64, n0 = blockIdx.x * 64;
  f32x4 acc[4];
  acc[0] = acc[1] = acc[2] = acc[3] = (f32x4)0.f;
  int soff[2];
  #pragma unroll
  for (int c = 0; c < 2; c++) {
    int idx = wv * 128 + c * 64 + l;
    int row = idx >> 3, bp = idx & 7;
    int cb = (bp ^ row) & 7;
    soff[c] = row * DM + cb * 8;
  }
  const unsigned short* asrc = xbf + (size_t)m0 * DM;
  const unsigned short* bsrc = wt + (size_t)n0 * DM;
  unsigned short* la = &a_lds[0][0];
  unsigned short* lb = &b_lds[0][0];

#define STAGE_AB(B, KK)                                              \
  do {                                                               \
    ASYNC16(asrc + (KK) + soff[0], la + (B)*4096 + wv * 1024);       \
    ASYNC16(asrc + (KK) + soff[1], la + (B)*4096 + wv * 1024 + 512); \
    ASYNC16(bsrc + (KK) + soff[0], lb + (B)*4096 + wv * 1024);       \
    ASYNC16(bsrc + (KK) + soff[1], lb + (B)*4096 + wv * 1024 + 512); \
  } while (0)

  STAGE_AB(0, 0);
  WAITB();
  for (int kk = 0; kk < DM; kk += 128) {
    STAGE_AB(1, kk + 64);
    gemm_body(&a_lds[0][0], &b_lds[0][0], acc, wv, l15, lg);
    WAITB();
    if (kk + 128 < DM) STAGE_AB(0, kk + 128);
    gemm_body(&a_lds[1][0], &b_lds[1][0], acc, wv, l15, lg);
    WAITB();
  }
#undef STAGE_AB
  const int mb = m0 + wv * 16 + lg * 4;
  #pragma unroll
  for (int nt = 0; nt < 4; nt++) {
    const int n = n0 + nt * 16 + l15;
    const float bv = bias[n];
    const int sec = n / DM;             // 0=q 1=k 2=v (uniform per tile)
    const int nn = n - sec * DM;
    const int h = nn >> 6, d = nn & 63;
    if (sec == 0) {
      #pragma unroll
      for (int r = 0; r < 4; r++)
        qb[((size_t)h * SL + mb + r) * 64 + d] = f2bf((acc[nt][r] + bv) * 0.180336880f);
    } else if (sec == 1) {
      #pragma unroll
      for (int r = 0; r < 4; r++)
        kbo[((size_t)h * SL + mb + r) * 64 + d] = f2bf(acc[nt][r] + bv);
    } else {
      u16x4 o;
      #pragma unroll
      for (int r = 0; r < 4; r++) o[r] = f2bf(acc[nt][r] + bv);
      *reinterpret_cast<u16x4*>(vt + ((size_t)h * 64 + d) * SL + mb) = o;
    }
  }
}

// 32x32 swapped attention body. Lane owns q = l&31; pair (l, l+32) splits 64 keys.
// Softmax: pure VALU (permlane32_swap cross-pair). P->B-frag: 4 cvt_pk + 2 swaps
// per k-chunk (T12). Defer-max (T13) skips corr-rescale when max growth <= 10 (log2).
__device__ __forceinline__ void attn_body32(
    const unsigned short* kb, const unsigned short* vb,
    const s16x8* qf, f32x16* ot, float& mrun, float& lrun,
    int l31, int s) {
  f32x16 st[2];
  __builtin_amdgcn_s_setprio(1);
  #pragma unroll
  for (int kt = 0; kt < 2; kt++) {
    f32x16 acc = (f32x16)0.f;
    #pragma unroll
    for (int c = 0; c < 4; c++) {
      s16x8 kf = *reinterpret_cast<const s16x8*>(&kb[aswz(kt * 32 + l31, c * 16 + s * 8)]);
      acc = __builtin_amdgcn_mfma_f32_32x32x16_bf16(kf, qf[c], acc, 0, 0, 0);
    }
    st[kt] = acc;
  }
  __builtin_amdgcn_s_setprio(0);
  // in-lane max tree over 32 scores
  float v8[8];
  #pragma unroll
  for (int i = 0; i < 8; i++)
    v8[i] = fmaxf(fmaxf(st[0][i], st[0][i + 8]), fmaxf(st[1][i], st[1][i + 8]));
  float m4a = fmaxf(v8[0], v8[4]), m4b = fmaxf(v8[1], v8[5]);
  float m4c = fmaxf(v8[2], v8[6]), m4d = fmaxf(v8[3], v8[7]);
  float tm = fmaxf(fmaxf(m4a, m4b), fmaxf(m4c, m4d));
  // cross-pair max: copy+swap gives lo-half / hi-half values lane-aligned
  float xa = tm, xb = tm;
  asm volatile("v_permlane32_swap_b32 %0, %1" : "+v"(xa), "+v"(xb));
  const float rowmax = fmaxf(xa, xb);
  if (!__all(rowmax <= mrun + 10.0f)) {
    const float mn = fmaxf(mrun, rowmax);
    const float corr = exp2f(mrun - mn);
    lrun *= corr;
    #pragma unroll
    for (int dt = 0; dt < 2; dt++)
      #pragma unroll
      for (int r = 0; r < 16; r++) ot[dt][r] *= corr;
    mrun = mn;
  }
  // exp2 + partial sums
  float p0 = 0.f, p1 = 0.f, p2 = 0.f, p3 = 0.f;
  #pragma unroll
  for (int kt = 0; kt < 2; kt++) {
    #pragma unroll
    for (int r = 0; r < 16; r += 4) {
      float e0 = exp2f(st[kt][r + 0] - mrun);
      float e1 = exp2f(st[kt][r + 1] - mrun);
      float e2 = exp2f(st[kt][r + 2] - mrun);
      float e3 = exp2f(st[kt][r + 3] - mrun);
      st[kt][r + 0] = e0; st[kt][r + 1] = e1;
      st[kt][r + 2] = e2; st[kt][r + 3] = e3;
      p0 += e0; p1 += e1; p2 += e2; p3 += e3;
    }
  }
  float psum = (p0 + p1) + (p2 + p3);
  float sa = psum, sb = psum;
  asm volatile("v_permlane32_swap_b32 %0, %1" : "+v"(sa), "+v"(sb));
  lrun += sa + sb;
  // P pack + PV. Chunk c covers keys c*16 + s*8 + 0..7 per lane.
  __builtin_amdgcn_s_setprio(1);
  #pragma unroll
  for (int c = 0; c < 4; c++) {
    const int kt = c >> 1, m0 = (c & 1) * 8;
    unsigned w0, w1, w2, w3;
    asm("v_cvt_pk_bf16_f32 %0, %1, %2" : "=v"(w0) : "v"(st[kt][m0 + 0]), "v"(st[kt][m0 + 1]));
    asm("v_cvt_pk_bf16_f32 %0, %1, %2" : "=v"(w1) : "v"(st[kt][m0 + 2]), "v"(st[kt][m0 + 3]));
    asm("v_cvt_pk_bf16_f32 %0, %1, %2" : "=v"(w2) : "v"(st[kt][m0 + 4]), "v"(st[kt][m0 + 5]));
    asm("v_cvt_pk_bf16_f32 %0, %1, %2" : "=v"(w3) : "v"(st[kt][m0 + 6]), "v"(st[kt][m0 + 7]));
    // (w0,w2) <- swap(q0,q4): w0 = keys +{0,1} all lanes, w2 = keys +{4,5}
    asm volatile("v_permlane32_swap_b32 %0, %1" : "+v"(w0), "+v"(w2));
    asm volatile("v_permlane32_swap_b32 %0, %1" : "+v"(w1), "+v"(w3));
    u32x4 wv_;
    wv_[0] = w0; wv_[1] = w1; wv_[2] = w2; wv_[3] = w3;
    s16x8 pbf = *reinterpret_cast<s16x8*>(&wv_);
    #pragma unroll
    for (int dt = 0; dt < 2; dt++) {
      s16x8 vf = *reinterpret_cast<const s16x8*>(&vb[aswz(dt * 32 + l31, c * 16 + s * 8)]);
      ot[dt] = __builtin_amdgcn_mfma_f32_32x32x16_bf16(vf, pbf, ot[dt], 0, 0, 0);
    }
  }
  __builtin_amdgcn_s_setprio(0);
}

// Flash attention: 2 warps x 32 q-rows, KVBLK=64, async dbuf, zero-DS softmax
extern "C" __global__ __launch_bounds__(128) void k_attn(
    const unsigned short* __restrict__ qb, const unsigned short* __restrict__ kbi,
    const unsigned short* __restrict__ vt, unsigned short* __restrict__ aout) {
  __shared__ alignas(16) unsigned short k_lds[2][4096];
  __shared__ alignas(16) unsigned short v_lds[2][4096];
  const int t = threadIdx.x, w = t >> 6, l = t & 63;
  const int l31 = l & 31, s = l >> 5;
  const int h = blockIdx.y;
  const int q0 = blockIdx.x * 64;
  const unsigned short* qh = qb + (size_t)h * SL * 64;
  const unsigned short* kh = kbi + (size_t)h * SL * 64;
  const unsigned short* vh = vt + (size_t)h * 64 * SL;
  const int q = q0 + w * 32 + l31;
  s16x8 qf[4];
  #pragma unroll
  for (int c = 0; c < 4; c++)
    qf[c] = *reinterpret_cast<const s16x8*>(qh + (size_t)q * 64 + c * 16 + s * 8);
  f32x16 ot[2];
  ot[0] = (f32x16)0.f;
  ot[1] = (f32x16)0.f;
  float mrun = -1e30f, lrun = 0.f;
  // staging: 512 16B-blocks per tile; thread covers blocks r*128 + w*64 + l.
  // source col-block pre-XORed so linear LDS dest realizes the aswz image.
  int koff[4], voff[4];
  #pragma unroll
  for (int r = 0; r < 4; r++) {
    int b = r * 128 + w * 64 + l;
    int R = b >> 3;
    int cb = (b & 7) ^ ((R ^ (R >> 3)) & 7);
    koff[r] = R * 64 + cb * 8;
    voff[r] = R * SL + cb * 8;
  }

#define STAGE_KV(B, KB0)                                                      \
  do {                                                                        \
    _Pragma("unroll")                                                         \
    for (int r = 0; r < 4; r++) {                                             \
      ASYNC16(kh + (size_t)(KB0) * 64 + koff[r],                              \
              &k_lds[B][0] + r * 1024 + w * 512);                             \
      ASYNC16(vh + (KB0) + voff[r],                                           \
              &v_lds[B][0] + r * 1024 + w * 512);                             \
    }                                                                         \
  } while (0)

  STAGE_KV(0, 0);
  WAITB();
  for (int kb0 = 0; kb0 < SL; kb0 += 128) {
    STAGE_KV(1, kb0 + 64);
    attn_body32(&k_lds[0][0], &v_lds[0][0], qf, ot, mrun, lrun, l31, s);
    WAITB();
    if (kb0 + 128 < SL) STAGE_KV(0, kb0 + 128);
    attn_body32(&k_lds[1][0], &v_lds[1][0], qf, ot, mrun, lrun, l31, s);
    WAITB();
  }
#undef STAGE_KV
  // O^T[d][q]: q lane-local; d = dt*32 + rg*8 + s*4 + j
  const float inv = 1.f / lrun;
  #pragma unroll
  for (int dt = 0; dt < 2; dt++) {
    #pragma unroll
    for (int rg = 0; rg < 4; rg++) {
      u16x4 o;
      #pragma unroll
      for (int j = 0; j < 4; j++) o[j] = f2bf(ot[dt][rg * 4 + j] * inv);
      *reinterpret_cast<u16x4*>(aout + (size_t)q * DM + h * 64 + dt * 32 + rg * 8 + s * 4) = o;
    }
  }
}

// out-proj GEMM + bias + residual -> y (fp32), async dbuf
extern "C" __global__ __launch_bounds__(256) void k_out(
    const unsigned short* __restrict__ abf, const unsigned short* __restrict__ wot,
    const float* __restrict__ bias, const float* __restrict__ x, float* __restrict__ y) {
  __shared__ alignas(16) unsigned short a_lds[2][4096];
  __shared__ alignas(16) unsigned short b_lds[2][4096];
  const int t = threadIdx.x, wv = t >> 6, l = t & 63;
  const int l15 = l & 15, lg = l >> 4;
  const int m0 = blockIdx.y * 64, n0 = blockIdx.x * 64;
  f32x4 acc[4];
  acc[0] = acc[1] = acc[2] = acc[3] = (f32x4)0.f;
  int soff[2];
  #pragma unroll
  for (int c = 0; c < 2; c++) {
    int idx = wv * 128 + c * 64 + l;
    int row = idx >> 3, bp = idx & 7;
    int cb = (bp ^ row) & 7;
    soff[c] = row * DM + cb * 8;
  }
  const unsigned short* asrc = abf + (size_t)m0 * DM;
  const unsigned short* bsrc = wot + (size_t)n0 * DM;
  unsigned short* la = &a_lds[0][0];
  unsigned short* lb = &b_lds[0][0];

#define STAGE_AB(B, KK)                                              \
  do {                                                               \
    ASYNC16(asrc + (KK) + soff[0], la + (B)*4096 + wv * 1024);       \
    ASYNC16(asrc + (KK) + soff[1], la + (B)*4096 + wv * 1024 + 512); \
    ASYNC16(bsrc + (KK) + soff[0], lb + (B)*4096 + wv * 1024);       \
    ASYNC16(bsrc + (KK) + soff[1], lb + (B)*4096 + wv * 1024 + 512); \
  } while (0)

  STAGE_AB(0, 0);
  WAITB();
  for (int kk = 0; kk < DM; kk += 128) {
    STAGE_AB(1, kk + 64);
    gemm_body(&a_lds[0][0], &b_lds[0][0], acc, wv, l15, lg);
    WAITB();
    if (kk + 128 < DM) STAGE_AB(0, kk + 128);
    gemm_body(&a_lds[1][0], &b_lds[1][0], acc, wv, l15, lg);
    WAITB();
  }
#undef STAGE_AB
  const int mb = m0 + wv * 16 + lg * 4;
  #pragma unroll
  for (int nt = 0; nt < 4; nt++) {
    const int n = n0 + nt * 16 + l15;
    const float bv = bias[n];
    #pragma unroll
    for (int r = 0; r < 4; r++)
      y[(size_t)(mb + r) * DM + n] = acc[nt][r] + bv + x[(size_t)(mb + r) * DM + n];
  }
}

extern "C" __global__ __launch_bounds__(256) void k_ln(
    const float* __restrict__ y, const float* __restrict__ g, const float* __restrict__ b,
    float* __restrict__ out) {
  const int row = blockIdx.x, t = threadIdx.x;
  const float* yr = y + (size_t)row * DM;
  float v0 = yr[t], v1 = yr[t + 256], v2 = yr[t + 512];
  float sum = v0 + v1 + v2;
  float sq = v0 * v0 + v1 * v1 + v2 * v2;
  #pragma unroll
  for (int off = 1; off < 64; off <<= 1) {
    sum += __shfl_xor(sum, off, 64);
    sq += __shfl_xor(sq, off, 64);
  }
  __shared__ float ls[8];
  const int wv = t >> 6, l = t & 63;
  if (l == 0) { ls[wv] = sum; ls[4 + wv] = sq; }
  __syncthreads();
  sum = ls[0] + ls[1] + ls[2] + ls[3];
  sq = ls[4] + ls[5] + ls[6] + ls[7];
  const float mu = sum * (1.f / DM);
  const float rstd = rsqrtf(sq * (1.f / DM) - mu * mu + 1e-5f);
  out[(size_t)row * DM + t] = (v0 - mu) * rstd * g[t] + b[t];
  out[(size_t)row * DM + t + 256] = (v1 - mu) * rstd * g[t + 256] + b[t + 256];
  out[(size_t)row * DM + t + 512] = (v2 - mu) * rstd * g[t + 512] + b[t + 512];
}

extern "C" void kernel_launch(void* const* d_in, const int* in_sizes, int n_in,
                              void* d_out, int out_size, void* d_ws, size_t ws_size,
                              hipStream_t stream) {
  (void)in_sizes; (void)n_in; (void)out_size; (void)ws_size;
  const float* x = (const float*)d_in[0];
  const float* Wa = (const float*)d_in[1];
  const float* ba = (const float*)d_in[2];
  const float* Wo = (const float*)d_in[3];
  const float* bo = (const float*)d_in[4];
  const float* lng = (const float*)d_in[5];
  const float* lnb = (const float*)d_in[6];
  float* out = (float*)d_out;

  unsigned short* ws16 = (unsigned short*)d_ws;
  unsigned short* xbf = ws16;                 // 4096x768
  unsigned short* wat = xbf + 3145728;        // 2304x768 (W_attn^T)
  unsigned short* wot = wat + 1769472;        // 768x768  (W_out^T)
  unsigned short* qbf = wot + 589824;         // [12][4096][64]
  unsigned short* kbf = qbf + 3145728;        // [12][4096][64]
  unsigned short* vtb = kbf + 3145728;        // [12][64][4096]
  unsigned short* aob = vtb + 3145728;        // 4096x768 attn out
  float* ybuf = (float*)(aob + 3145728);      // 4096x768 fp32

  k_cvt<<<3072, 256, 0, stream>>>(x, xbf, 3145728);
  k_tr<<<dim3(36, 12), 256, 0, stream>>>(Wa, wat, 768, 2304);
  k_tr<<<dim3(12, 12), 256, 0, stream>>>(Wo, wot, 768, 768);
  k_qkv<<<dim3(36, 64), 256, 0, stream>>>(xbf, wat, ba, qbf, kbf, vtb);
  k_attn<<<dim3(64, 12), 128, 0, stream>>>(qbf, kbf, vtb, aob);
  k_out<<<dim3(12, 64), 256, 0, stream>>>(aob, wot, bo, x, ybuf);
  k_ln<<<4096, 256, 0, stream>>>(ybuf, lng, lnb, out);
}

// Round 5
// 179.313 us; speedup vs baseline: 1.2082x; 1.2082x over previous
//
#include <hip/hip_runtime.h>
#include <cstdint>
#include <cstddef>

#define SL 4096
#define DM 768

typedef short s16x8 __attribute__((ext_vector_type(8)));
typedef unsigned short u16x8 __attribute__((ext_vector_type(8)));
typedef unsigned short u16x4 __attribute__((ext_vector_type(4)));
typedef float f32x4 __attribute__((ext_vector_type(4)));
typedef float f32x16 __attribute__((ext_vector_type(16)));
typedef unsigned int u32x4 __attribute__((ext_vector_type(4)));

__device__ __forceinline__ unsigned short f2bf(float f) {
  unsigned u = __float_as_uint(f);
  u = u + 0x7fffu + ((u >> 16) & 1u);   // round-to-nearest-even
  return (unsigned short)(u >> 16);
}

// 16B-block XOR swizzle within a 64-short (128B) row (guide G4/T2) — GEMM kernels.
__device__ __forceinline__ int swz(int row, int col) {
  return (row << 6) + ((((col >> 3) ^ row) & 7) << 3) + (col & 7);
}

// attention K-tile swizzle (rows = keys 0..31, 64-short rows)
__device__ __forceinline__ int aswz(int row, int col) {
  return (row << 6) + ((((col >> 3) ^ row ^ (row >> 3)) & 7) << 3) + (col & 7);
}

// attention V-tile swizzle (rows = d 0..63, 32-short rows; 4 blocks/row)
__device__ __forceinline__ int vswz(int d, int col) {
  return (d << 5) + ((((col >> 3) ^ (d >> 1)) & 3) << 3) + (col & 7);
}

// async global->LDS, 16B per lane; dest = wave-uniform base (+lane*16 implicit),
// source per-lane address carries the swizzle (m173 pattern).
#define ASYNC16(G, L)                                                        \
  __builtin_amdgcn_global_load_lds(                                          \
      (const __attribute__((address_space(1))) void*)(G),                    \
      (__attribute__((address_space(3))) void*)(L), 16, 0, 0)

#define WAITB()                                   \
  do {                                            \
    asm volatile("s_waitcnt vmcnt(0)" ::: "memory"); \
    __builtin_amdgcn_s_barrier();                 \
  } while (0)

extern "C" __global__ __launch_bounds__(256) void k_cvt(
    const float* __restrict__ in, unsigned short* __restrict__ out, int n) {
  int i = (blockIdx.x * 256 + threadIdx.x) * 4;
  if (i >= n) return;
  f32x4 v = *reinterpret_cast<const f32x4*>(in + i);
  u16x4 o;
  o[0] = f2bf(v[0]); o[1] = f2bf(v[1]); o[2] = f2bf(v[2]); o[3] = f2bf(v[3]);
  *reinterpret_cast<u16x4*>(out + i) = o;
}

// fp32 [R][C] -> bf16 [C][R], 64x64 tiles
extern "C" __global__ __launch_bounds__(256) void k_tr(
    const float* __restrict__ in, unsigned short* __restrict__ out, int R, int C) {
  __shared__ float tile[64][65];
  const int t = threadIdx.x;
  const int r0 = blockIdx.y * 64, c0 = blockIdx.x * 64;
  const int lr = t >> 2, lcb = (t & 3) * 16;
  #pragma unroll
  for (int j = 0; j < 16; j += 4) {
    f32x4 v = *reinterpret_cast<const f32x4*>(in + (size_t)(r0 + lr) * C + c0 + lcb + j);
    tile[lr][lcb + j + 0] = v[0];
    tile[lr][lcb + j + 1] = v[1];
    tile[lr][lcb + j + 2] = v[2];
    tile[lr][lcb + j + 3] = v[3];
  }
  __syncthreads();
  #pragma unroll
  for (int j = 0; j < 16; j += 4) {
    u16x4 o;
    o[0] = f2bf(tile[lcb + j + 0][lr]);
    o[1] = f2bf(tile[lcb + j + 1][lr]);
    o[2] = f2bf(tile[lcb + j + 2][lr]);
    o[3] = f2bf(tile[lcb + j + 3][lr]);
    *reinterpret_cast<u16x4*>(out + (size_t)(c0 + lr) * R + r0 + lcb + j) = o;
  }
}

__device__ __forceinline__ void gemm_body(
    const unsigned short* al, const unsigned short* bl, f32x4* acc,
    int wv, int l15, int lg) {
  #pragma unroll
  for (int kc = 0; kc < 2; kc++) {
    s16x8 af = *reinterpret_cast<const s16x8*>(&al[swz(wv * 16 + l15, kc * 32 + lg * 8)]);
    #pragma unroll
    for (int nt = 0; nt < 4; nt++) {
      s16x8 bfr = *reinterpret_cast<const s16x8*>(&bl[swz(nt * 16 + l15, kc * 32 + lg * 8)]);
      acc[nt] = __builtin_amdgcn_mfma_f32_16x16x32_bf16(af, bfr, acc[nt], 0, 0, 0);
    }
  }
}

// QKV GEMM (async dbuf): q pre-scaled by 0.125*log2(e), k row-major, v transposed
extern "C" __global__ __launch_bounds__(256) void k_qkv(
    const unsigned short* __restrict__ xbf, const unsigned short* __restrict__ wt,
    const float* __restrict__ bias, unsigned short* __restrict__ qb,
    unsigned short* __restrict__ kbo, unsigned short* __restrict__ vt) {
  __shared__ alignas(16) unsigned short a_lds[2][4096];
  __shared__ alignas(16) unsigned short b_lds[2][4096];
  const int t = threadIdx.x, wv = t >> 6, l = t & 63;
  const int l15 = l & 15, lg = l >> 4;
  const int m0 = blockIdx.y * 64, n0 = blockIdx.x * 64;
  f32x4 acc[4];
  acc[0] = acc[1] = acc[2] = acc[3] = (f32x4)0.f;
  int soff[2];
  #pragma unroll
  for (int c = 0; c < 2; c++) {
    int idx = wv * 128 + c * 64 + l;
    int row = idx >> 3, bp = idx & 7;
    int cb = (bp ^ row) & 7;
    soff[c] = row * DM + cb * 8;
  }
  const unsigned short* asrc = xbf + (size_t)m0 * DM;
  const unsigned short* bsrc = wt + (size_t)n0 * DM;
  unsigned short* la = &a_lds[0][0];
  unsigned short* lb = &b_lds[0][0];

#define STAGE_AB(B, KK)                                              \
  do {                                                               \
    ASYNC16(asrc + (KK) + soff[0], la + (B)*4096 + wv * 1024);       \
    ASYNC16(asrc + (KK) + soff[1], la + (B)*4096 + wv * 1024 + 512); \
    ASYNC16(bsrc + (KK) + soff[0], lb + (B)*4096 + wv * 1024);       \
    ASYNC16(bsrc + (KK) + soff[1], lb + (B)*4096 + wv * 1024 + 512); \
  } while (0)

  STAGE_AB(0, 0);
  WAITB();
  for (int kk = 0; kk < DM; kk += 128) {
    STAGE_AB(1, kk + 64);
    gemm_body(&a_lds[0][0], &b_lds[0][0], acc, wv, l15, lg);
    WAITB();
    if (kk + 128 < DM) STAGE_AB(0, kk + 128);
    gemm_body(&a_lds[1][0], &b_lds[1][0], acc, wv, l15, lg);
    WAITB();
  }
#undef STAGE_AB
  const int mb = m0 + wv * 16 + lg * 4;
  #pragma unroll
  for (int nt = 0; nt < 4; nt++) {
    const int n = n0 + nt * 16 + l15;
    const float bv = bias[n];
    const int sec = n / DM;             // 0=q 1=k 2=v (uniform per tile)
    const int nn = n - sec * DM;
    const int h = nn >> 6, d = nn & 63;
    if (sec == 0) {
      #pragma unroll
      for (int r = 0; r < 4; r++)
        qb[((size_t)h * SL + mb + r) * 64 + d] = f2bf((acc[nt][r] + bv) * 0.180336880f);
    } else if (sec == 1) {
      #pragma unroll
      for (int r = 0; r < 4; r++)
        kbo[((size_t)h * SL + mb + r) * 64 + d] = f2bf(acc[nt][r] + bv);
    } else {
      u16x4 o;
      #pragma unroll
      for (int r = 0; r < 4; r++) o[r] = f2bf(acc[nt][r] + bv);
      *reinterpret_cast<u16x4*>(vt + ((size_t)h * 64 + d) * SL + mb) = o;
    }
  }
}

// 32x32 swapped attention body, KVBLK=32. Lane owns q = l&31; pair (l, l+32)
// splits the 32 keys (16 scores each). Softmax pure-VALU via permlane32_swap.
__device__ __forceinline__ void attn_body32s(
    const unsigned short* kb, const unsigned short* vb,
    const s16x8* qf, f32x16* ot, float& mrun, float& lrun,
    int l31, int s) {
  f32x16 st = (f32x16)0.f;
  __builtin_amdgcn_s_setprio(1);
  #pragma unroll
  for (int c = 0; c < 4; c++) {
    s16x8 kf = *reinterpret_cast<const s16x8*>(&kb[aswz(l31, c * 16 + s * 8)]);
    st = __builtin_amdgcn_mfma_f32_32x32x16_bf16(kf, qf[c], st, 0, 0, 0);
  }
  __builtin_amdgcn_s_setprio(0);
  // in-lane max tree over 16 scores
  float m8[8];
  #pragma unroll
  for (int i = 0; i < 8; i++) m8[i] = fmaxf(st[i], st[i + 8]);
  float m4a = fmaxf(m8[0], m8[4]), m4b = fmaxf(m8[1], m8[5]);
  float m4c = fmaxf(m8[2], m8[6]), m4d = fmaxf(m8[3], m8[7]);
  float tm = fmaxf(fmaxf(m4a, m4b), fmaxf(m4c, m4d));
  float xa = tm, xb = tm;
  asm volatile("v_permlane32_swap_b32 %0, %1" : "+v"(xa), "+v"(xb));
  const float rowmax = fmaxf(xa, xb);
  if (!__all(rowmax <= mrun + 10.0f)) {          // defer-max (T13), log2 domain
    const float mn = fmaxf(mrun, rowmax);
    const float corr = exp2f(mrun - mn);
    lrun *= corr;
    #pragma unroll
    for (int dt = 0; dt < 2; dt++)
      #pragma unroll
      for (int r = 0; r < 16; r++) ot[dt][r] *= corr;
    mrun = mn;
  }
  float p0 = 0.f, p1 = 0.f, p2 = 0.f, p3 = 0.f;
  #pragma unroll
  for (int r = 0; r < 16; r += 4) {
    float e0 = exp2f(st[r + 0] - mrun);
    float e1 = exp2f(st[r + 1] - mrun);
    float e2 = exp2f(st[r + 2] - mrun);
    float e3 = exp2f(st[r + 3] - mrun);
    st[r + 0] = e0; st[r + 1] = e1; st[r + 2] = e2; st[r + 3] = e3;
    p0 += e0; p1 += e1; p2 += e2; p3 += e3;
  }
  float psum = (p0 + p1) + (p2 + p3);
  float sa = psum, sb = psum;
  asm volatile("v_permlane32_swap_b32 %0, %1" : "+v"(sa), "+v"(sb));
  lrun += sa + sb;
  // P pack + PV: chunk m covers keys m*16 + s*8 + 0..7 per lane
  __builtin_amdgcn_s_setprio(1);
  #pragma unroll
  for (int m = 0; m < 2; m++) {
    const int m0 = m * 8;
    unsigned w0, w1, w2, w3;
    asm("v_cvt_pk_bf16_f32 %0, %1, %2" : "=v"(w0) : "v"(st[m0 + 0]), "v"(st[m0 + 1]));
    asm("v_cvt_pk_bf16_f32 %0, %1, %2" : "=v"(w1) : "v"(st[m0 + 2]), "v"(st[m0 + 3]));
    asm("v_cvt_pk_bf16_f32 %0, %1, %2" : "=v"(w2) : "v"(st[m0 + 4]), "v"(st[m0 + 5]));
    asm("v_cvt_pk_bf16_f32 %0, %1, %2" : "=v"(w3) : "v"(st[m0 + 6]), "v"(st[m0 + 7]));
    asm volatile("v_permlane32_swap_b32 %0, %1" : "+v"(w0), "+v"(w2));
    asm volatile("v_permlane32_swap_b32 %0, %1" : "+v"(w1), "+v"(w3));
    u32x4 wv_;
    wv_[0] = w0; wv_[1] = w1; wv_[2] = w2; wv_[3] = w3;
    s16x8 pbf = *reinterpret_cast<s16x8*>(&wv_);
    #pragma unroll
    for (int dt = 0; dt < 2; dt++) {
      s16x8 vf = *reinterpret_cast<const s16x8*>(&vb[vswz(dt * 32 + l31, m * 16 + s * 8)]);
      ot[dt] = __builtin_amdgcn_mfma_f32_32x32x16_bf16(vf, pbf, ot[dt], 0, 0, 0);
    }
  }
  __builtin_amdgcn_s_setprio(0);
}

// Flash attention: 4 waves = 2 q-subtiles x 2 KV-halves; KVBLK=32; async dbuf;
// in-LDS merge of the two halves' online-softmax states; XCD head-clustering.
extern "C" __global__ __launch_bounds__(256) void k_attn(
    const unsigned short* __restrict__ qb, const unsigned short* __restrict__ kbi,
    const unsigned short* __restrict__ vt, unsigned short* __restrict__ aout) {
  __shared__ alignas(16) unsigned short k_lds[2][2][2048];  // [half][buf][32k x 64d]
  __shared__ alignas(16) unsigned short v_lds[2][2][2048];  // [half][buf][64d x 32k]
  __shared__ float o_mrg[2][32][68];
  __shared__ float ml_mrg[2][32][2];
  const int t = threadIdx.x, w = t >> 6, l = t & 63;
  const int l31 = l & 31, s = l >> 5;
  const int half = w >> 1, qs = w & 1;
  // XCD swizzle: each XCD gets 96 consecutive head-major ids (<=2 heads' KV in L2)
  const int bid = blockIdx.x;
  const int sid = (bid & 7) * 96 + (bid >> 3);
  const int h = sid >> 6, qt = sid & 63;
  const unsigned short* qh = qb + (size_t)h * SL * 64;
  const unsigned short* kh = kbi + (size_t)h * SL * 64 + (size_t)half * 2048 * 64;
  const unsigned short* vh = vt + (size_t)h * 64 * SL + half * 2048;
  const int q = qt * 64 + qs * 32 + l31;
  s16x8 qf[4];
  #pragma unroll
  for (int c = 0; c < 4; c++)
    qf[c] = *reinterpret_cast<const s16x8*>(qh + (size_t)q * 64 + c * 16 + s * 8);
  f32x16 ot[2];
  ot[0] = (f32x16)0.f;
  ot[1] = (f32x16)0.f;
  float mrun = -1e30f, lrun = 0.f;
  // staging offsets: wave covers 16B-blocks (qs*2+c)*64 + l of its half's tiles
  int koff[2], voff[2];
  #pragma unroll
  for (int c = 0; c < 2; c++) {
    int i = (qs * 2 + c) * 64 + l;
    int key = i >> 3, kb_ = i & 7;
    koff[c] = key * 64 + (kb_ ^ ((key ^ (key >> 3)) & 7)) * 8;
    int d = i >> 2, vb_ = i & 3;
    voff[c] = d * SL + (vb_ ^ ((d >> 1) & 3)) * 8;
  }

#define STAGE_KV(B, LB)                                                     \
  do {                                                                      \
    _Pragma("unroll")                                                       \
    for (int c = 0; c < 2; c++) {                                           \
      ASYNC16(kh + (size_t)(LB) * 64 + koff[c],                             \
              &k_lds[half][B][0] + (qs * 2 + c) * 512);                     \
      ASYNC16(vh + (LB) + voff[c],                                          \
              &v_lds[half][B][0] + (qs * 2 + c) * 512);                     \
    }                                                                       \
  } while (0)

  STAGE_KV(0, 0);
  WAITB();
  for (int lb = 0; lb < 2048; lb += 64) {
    STAGE_KV(1, lb + 32);
    attn_body32s(&k_lds[half][0][0], &v_lds[half][0][0], qf, ot, mrun, lrun, l31, s);
    WAITB();
    if (lb + 64 < 2048) STAGE_KV(0, lb + 64);
    attn_body32s(&k_lds[half][1][0], &v_lds[half][1][0], qf, ot, mrun, lrun, l31, s);
    WAITB();
  }
#undef STAGE_KV
  // merge the two halves' (m, l, O) via LDS; d(r) = dt*32 + 8*(r>>2) + 4*s + (r&3)
  if (half == 1) {
    #pragma unroll
    for (int dt = 0; dt < 2; dt++) {
      #pragma unroll
      for (int rq = 0; rq < 4; rq++) {
        f32x4 v;
        #pragma unroll
        for (int j = 0; j < 4; j++) v[j] = ot[dt][rq * 4 + j];
        *reinterpret_cast<f32x4*>(&o_mrg[qs][l31][dt * 32 + rq * 8 + s * 4]) = v;
      }
    }
    if (s == 0) {
      ml_mrg[qs][l31][0] = mrun;
      ml_mrg[qs][l31][1] = lrun;
    }
  }
  __syncthreads();
  if (half == 0) {
    const float mB = ml_mrg[qs][l31][0], lB = ml_mrg[qs][l31][1];
    const float mn = fmaxf(mrun, mB);
    const float cA = exp2f(mrun - mn), cB = exp2f(mB - mn);
    const float linv = 1.f / (lrun * cA + lB * cB);
    #pragma unroll
    for (int dt = 0; dt < 2; dt++) {
      #pragma unroll
      for (int rq = 0; rq < 4; rq++) {
        f32x4 vb_ = *reinterpret_cast<const f32x4*>(&o_mrg[qs][l31][dt * 32 + rq * 8 + s * 4]);
        u16x4 o;
        #pragma unroll
        for (int j = 0; j < 4; j++)
          o[j] = f2bf((ot[dt][rq * 4 + j] * cA + vb_[j] * cB) * linv);
        *reinterpret_cast<u16x4*>(aout + (size_t)q * DM + h * 64 + dt * 32 + rq * 8 + s * 4) = o;
      }
    }
  }
}

// out-proj GEMM + bias + residual -> y (fp32), async dbuf
extern "C" __global__ __launch_bounds__(256) void k_out(
    const unsigned short* __restrict__ abf, const unsigned short* __restrict__ wot,
    const float* __restrict__ bias, const float* __restrict__ x, float* __restrict__ y) {
  __shared__ alignas(16) unsigned short a_lds[2][4096];
  __shared__ alignas(16) unsigned short b_lds[2][4096];
  const int t = threadIdx.x, wv = t >> 6, l = t & 63;
  const int l15 = l & 15, lg = l >> 4;
  const int m0 = blockIdx.y * 64, n0 = blockIdx.x * 64;
  f32x4 acc[4];
  acc[0] = acc[1] = acc[2] = acc[3] = (f32x4)0.f;
  int soff[2];
  #pragma unroll
  for (int c = 0; c < 2; c++) {
    int idx = wv * 128 + c * 64 + l;
    int row = idx >> 3, bp = idx & 7;
    int cb = (bp ^ row) & 7;
    soff[c] = row * DM + cb * 8;
  }
  const unsigned short* asrc = abf + (size_t)m0 * DM;
  const unsigned short* bsrc = wot + (size_t)n0 * DM;
  unsigned short* la = &a_lds[0][0];
  unsigned short* lb = &b_lds[0][0];

#define STAGE_AB(B, KK)                                              \
  do {                                                               \
    ASYNC16(asrc + (KK) + soff[0], la + (B)*4096 + wv * 1024);       \
    ASYNC16(asrc + (KK) + soff[1], la + (B)*4096 + wv * 1024 + 512); \
    ASYNC16(bsrc + (KK) + soff[0], lb + (B)*4096 + wv * 1024);       \
    ASYNC16(bsrc + (KK) + soff[1], lb + (B)*4096 + wv * 1024 + 512); \
  } while (0)

  STAGE_AB(0, 0);
  WAITB();
  for (int kk = 0; kk < DM; kk += 128) {
    STAGE_AB(1, kk + 64);
    gemm_body(&a_lds[0][0], &b_lds[0][0], acc, wv, l15, lg);
    WAITB();
    if (kk + 128 < DM) STAGE_AB(0, kk + 128);
    gemm_body(&a_lds[1][0], &b_lds[1][0], acc, wv, l15, lg);
    WAITB();
  }
#undef STAGE_AB
  const int mb = m0 + wv * 16 + lg * 4;
  #pragma unroll
  for (int nt = 0; nt < 4; nt++) {
    const int n = n0 + nt * 16 + l15;
    const float bv = bias[n];
    #pragma unroll
    for (int r = 0; r < 4; r++)
      y[(size_t)(mb + r) * DM + n] = acc[nt][r] + bv + x[(size_t)(mb + r) * DM + n];
  }
}

extern "C" __global__ __launch_bounds__(256) void k_ln(
    const float* __restrict__ y, const float* __restrict__ g, const float* __restrict__ b,
    float* __restrict__ out) {
  const int row = blockIdx.x, t = threadIdx.x;
  const float* yr = y + (size_t)row * DM;
  float v0 = yr[t], v1 = yr[t + 256], v2 = yr[t + 512];
  float sum = v0 + v1 + v2;
  float sq = v0 * v0 + v1 * v1 + v2 * v2;
  #pragma unroll
  for (int off = 1; off < 64; off <<= 1) {
    sum += __shfl_xor(sum, off, 64);
    sq += __shfl_xor(sq, off, 64);
  }
  __shared__ float ls[8];
  const int wv = t >> 6, l = t & 63;
  if (l == 0) { ls[wv] = sum; ls[4 + wv] = sq; }
  __syncthreads();
  sum = ls[0] + ls[1] + ls[2] + ls[3];
  sq = ls[4] + ls[5] + ls[6] + ls[7];
  const float mu = sum * (1.f / DM);
  const float rstd = rsqrtf(sq * (1.f / DM) - mu * mu + 1e-5f);
  out[(size_t)row * DM + t] = (v0 - mu) * rstd * g[t] + b[t];
  out[(size_t)row * DM + t + 256] = (v1 - mu) * rstd * g[t + 256] + b[t + 256];
  out[(size_t)row * DM + t + 512] = (v2 - mu) * rstd * g[t + 512] + b[t + 512];
}

extern "C" void kernel_launch(void* const* d_in, const int* in_sizes, int n_in,
                              void* d_out, int out_size, void* d_ws, size_t ws_size,
                              hipStream_t stream) {
  (void)in_sizes; (void)n_in; (void)out_size; (void)ws_size;
  const float* x = (const float*)d_in[0];
  const float* Wa = (const float*)d_in[1];
  const float* ba = (const float*)d_in[2];
  const float* Wo = (const float*)d_in[3];
  const float* bo = (const float*)d_in[4];
  const float* lng = (const float*)d_in[5];
  const float* lnb = (const float*)d_in[6];
  float* out = (float*)d_out;

  unsigned short* ws16 = (unsigned short*)d_ws;
  unsigned short* xbf = ws16;                 // 4096x768
  unsigned short* wat = xbf + 3145728;        // 2304x768 (W_attn^T)
  unsigned short* wot = wat + 1769472;        // 768x768  (W_out^T)
  unsigned short* qbf = wot + 589824;         // [12][4096][64]
  unsigned short* kbf = qbf + 3145728;        // [12][4096][64]
  unsigned short* vtb = kbf + 3145728;        // [12][64][4096]
  unsigned short* aob = vtb + 3145728;        // 4096x768 attn out
  float* ybuf = (float*)(aob + 3145728);      // 4096x768 fp32

  k_cvt<<<3072, 256, 0, stream>>>(x, xbf, 3145728);
  k_tr<<<dim3(36, 12), 256, 0, stream>>>(Wa, wat, 768, 2304);
  k_tr<<<dim3(12, 12), 256, 0, stream>>>(Wo, wot, 768, 768);
  k_qkv<<<dim3(36, 64), 256, 0, stream>>>(xbf, wat, ba, qbf, kbf, vtb);
  k_attn<<<768, 256, 0, stream>>>(qbf, kbf, vtb, aob);
  k_out<<<dim3(12, 64), 256, 0, stream>>>(aob, wot, bo, x, ybuf);
  k_ln<<<4096, 256, 0, stream>>>(ybuf, lng, lnb, out);
}